// Round 7
// baseline (138.127 us; speedup 1.0000x reference)
//
#include <hip/hip_runtime.h>

#define NN    8192
#define INF_  256
#define OUTF  64
#define NH    2
#define NE    262144
#define CAP   256
#define DEGS  16
#define SLOPE 0.2f
#define NBLK  512

typedef __attribute__((ext_vector_type(8))) short short8;
typedef __attribute__((ext_vector_type(4))) float f32x4;
typedef __attribute__((ext_vector_type(2))) long long ll2;

__device__ __forceinline__ unsigned short f2bf(float f) {
  unsigned int u = __float_as_uint(f);
  u += 0x7fffu + ((u >> 16) & 1u);   // round-to-nearest-even
  return (unsigned short)(u >> 16);
}
__device__ __forceinline__ float bf2f(unsigned short u) {
  return __uint_as_float(((unsigned int)u) << 16);
}

// Device-scope arrive+release barrier. bar[0]=count, bar[1]=release flag;
// both zeroed by hipMemsetAsync before each launch (replay-safe).
__device__ __forceinline__ void grid_barrier(unsigned* bar) {
  __syncthreads();
  if (threadIdx.x == 0) {
    __threadfence();
    const unsigned arrived =
        __hip_atomic_fetch_add(&bar[0], 1u, __ATOMIC_ACQ_REL, __HIP_MEMORY_SCOPE_AGENT) + 1u;
    if (arrived == (unsigned)NBLK) {
      __hip_atomic_store(&bar[1], 1u, __ATOMIC_RELEASE, __HIP_MEMORY_SCOPE_AGENT);
    } else {
      while (__hip_atomic_load(&bar[1], __ATOMIC_ACQUIRE, __HIP_MEMORY_SCOPE_AGENT) == 0u)
        __builtin_amdgcn_s_sleep(2);
    }
    __threadfence();
  }
  __syncthreads();
}

__global__ __launch_bounds__(256, 2) void fused_kernel(
    const float* __restrict__ x, const int* __restrict__ ei,
    const float* __restrict__ W, const float* __restrict__ a1,
    const float* __restrict__ a2, unsigned* __restrict__ bar,
    int* __restrict__ deg, int* __restrict__ cols,
    unsigned short* __restrict__ xhb, float2* __restrict__ s1v,
    float2* __restrict__ s2v, float* __restrict__ out) {
  const int b = blockIdx.x, t = threadIdx.x;

  // ---- int64-vs-int32 edge detect (block-local; words 1..511 safe in both) ----
  __shared__ int s_nz;
  if (t == 0) s_nz = 0;
  __syncthreads();
  if (((const unsigned int*)ei)[2 * t + 1] != 0u) s_nz = 1;
  __syncthreads();
  const bool is64 = (s_nz == 0);

  // ---- Phase B1: GEMM stripe (rows 16b..16b+15), W read directly as f32 ----
  {
    const int l = t & 63, w = t >> 6;
    const int lo = l & 15, hi = l >> 4;
    const int n0 = b * 16;
    __shared__ float p1s[4][16], p2s[4][16];

    short8 bw[2][8];
    float a1c[2], a2c[2];
    int hq[2], colq[2];
#pragma unroll
    for (int q = 0; q < 2; ++q) {
      const int tc = w * 2 + q;
      const int h = tc >> 2;
      const int col = (tc * 16 + lo) & 63;
      hq[q] = h; colq[q] = col;
      a1c[q] = a1[h * OUTF + col];
      a2c[q] = a2[h * OUTF + col];
#pragma unroll
      for (int ks = 0; ks < 8; ++ks) {
        const float* wp = W + (size_t)h * (INF_ * OUTF) + (size_t)(ks * 32 + hi * 8) * OUTF + col;
        short8 bf;
#pragma unroll
        for (int m = 0; m < 8; ++m) bf[m] = (short)f2bf(wp[m * OUTF]);
        bw[q][ks] = bf;
      }
    }
    const float* xp = x + (size_t)(n0 + lo) * INF_ + hi * 8;
    short8 afr[8];
#pragma unroll
    for (int ks = 0; ks < 8; ++ks) {
      const float4 f0 = *(const float4*)(xp + ks * 32);
      const float4 f1 = *(const float4*)(xp + ks * 32 + 4);
      short8 a;
      a[0] = (short)f2bf(f0.x); a[1] = (short)f2bf(f0.y);
      a[2] = (short)f2bf(f0.z); a[3] = (short)f2bf(f0.w);
      a[4] = (short)f2bf(f1.x); a[5] = (short)f2bf(f1.y);
      a[6] = (short)f2bf(f1.z); a[7] = (short)f2bf(f1.w);
      afr[ks] = a;
    }
    f32x4 acc[2] = {};
#pragma unroll
    for (int ks = 0; ks < 8; ++ks)
#pragma unroll
      for (int q = 0; q < 2; ++q)
        acc[q] = __builtin_amdgcn_mfma_f32_16x16x32_bf16(afr[ks], bw[q][ks], acc[q], 0, 0, 0);
    // xh in bf16 (halves agg gather traffic)
#pragma unroll
    for (int q = 0; q < 2; ++q)
#pragma unroll
      for (int r = 0; r < 4; ++r)
        xhb[((size_t)hq[q] * NN + n0 + hi * 4 + r) * OUTF + colq[q]] = f2bf(acc[q][r]);
    // s1/s2 from f32 accumulator
#pragma unroll
    for (int r = 0; r < 4; ++r) {
      float p1 = acc[0][r] * a1c[0] + acc[1][r] * a1c[1];
      float p2 = acc[0][r] * a2c[0] + acc[1][r] * a2c[1];
#pragma unroll
      for (int s = 1; s < 16; s <<= 1) {
        p1 += __shfl_xor(p1, s, 64);
        p2 += __shfl_xor(p2, s, 64);
      }
      if (lo == 0) {
        p1s[w][hi * 4 + r] = p1;
        p2s[w][hi * 4 + r] = p2;
      }
    }
    __syncthreads();
    if (t < 16) {
      float2 v1, v2;
      v1.x = p1s[0][t] + p1s[1][t];  v1.y = p1s[2][t] + p1s[3][t];
      v2.x = p2s[0][t] + p2s[1][t];  v2.y = p2s[2][t] + p2s[3][t];
      s1v[n0 + t] = v1;
      s2v[n0 + t] = v2;
    }
  }

  // ---- Phase B2: edge scatter (512 edges per block, 2 per thread) ----
  {
    const int e0 = b * 512 + t * 2;
    int i0, j0, i1, j1;
    if (is64) {
      const ll2 a = *(const ll2*)((const long long*)ei + e0);
      const ll2 c = *(const ll2*)((const long long*)ei + NE + e0);
      i0 = (int)a[0]; i1 = (int)a[1]; j0 = (int)c[0]; j1 = (int)c[1];
    } else {
      const int2 a = *(const int2*)(ei + e0);
      const int2 c = *(const int2*)(ei + NE + e0);
      i0 = a.x; i1 = a.y; j0 = c.x; j1 = c.y;
    }
    const int p0 = atomicAdd(&deg[i0 * DEGS], 1);
    if (p0 < CAP) cols[i0 * CAP + p0] = j0;
    const int p1 = atomicAdd(&deg[i1 * DEGS], 1);
    if (p1 < CAP) cols[i1 * CAP + p1] = j1;
  }

  grid_barrier(bar);

  // ---- Phase C: aggregation, 16 nodes/block (2 per iter via 128-thr halves) ----
  __shared__ unsigned int bm[2][NN / 32];
  __shared__ unsigned long long vmask[2];
  const int half = t >> 7, th = t & 127, h = th >> 6, lane = th & 63;
  const unsigned short* basep = xhb + (size_t)h * NN * OUTF;
  const int r8 = lane >> 3, c8 = lane & 7;

  for (int it = 0; it < 8; ++it) {
    const int n = b * 16 + it * 2 + half;
    int dv = deg[n * DEGS];
    if (dv > CAP) dv = CAP;
    const int d = __builtin_amdgcn_readfirstlane(dv);
    bm[half][th] = 0u; bm[half][th + 128] = 0u;
    const bool fast = (d >= 1 && d <= 64);
    int j = 0;
    const bool valid = lane < d;
    if (fast && valid) j = cols[n * CAP + lane];
    __syncthreads();                        // bm zeroed
    if (fast && h == 0) {
      bool dup = false;
      if (valid) {
        const unsigned int old = atomicOr(&bm[half][j >> 5], 1u << (j & 31));
        dup = (old >> (j & 31)) & 1u;
      }
      const unsigned long long bal = __ballot(valid && !dup);
      if (lane == 0) vmask[half] = bal;
    }
    __syncthreads();                        // vmask ready

    if (d == 0) {
      // reference: all-NEG row -> uniform softmax over ALL nodes (never hit)
      float acc = 0.f;
      for (int p = 0; p < NN; ++p) acc += bf2f(basep[(size_t)p * OUTF + lane]);
      out[(size_t)n * (NH * OUTF) + h * OUTF + lane] = acc * (1.f / (float)NN);
    } else if (fast) {
      const bool kp = (vmask[half] >> lane) & 1ull;
      float sc = -1e30f;
      if (kp) {
        const float2 s1i2 = s1v[n];
        const float2 s2j2 = s2v[j];
        sc = (h ? s1i2.y : s1i2.x) + (h ? s2j2.y : s2j2.x);
        sc = (sc >= 0.f) ? sc : SLOPE * sc;
      }
      float m = sc;
#pragma unroll
      for (int s = 32; s > 0; s >>= 1) m = fmaxf(m, __shfl_xor(m, s, 64));
      const float wt = kp ? __expf(sc - m) : 0.f;
      float ds = wt;
#pragma unroll
      for (int s = 32; s > 0; s >>= 1) ds += __shfl_xor(ds, s, 64);
      const float inv = 1.f / ds;
      // gather: 8 rows per dwordx4 (row-slot r8, feat-chunk c8)
      float accv[8] = {0.f, 0.f, 0.f, 0.f, 0.f, 0.f, 0.f, 0.f};
      for (int p = 0; p < d; p += 8) {
        const int pr = p + r8;
        float ww = __shfl(wt, pr, 64);
        int   jj = __shfl(j,  pr, 64);
        ww = (pr < d) ? ww : 0.f;
        jj = (ww > 0.f) ? jj : 0;
        const short8 v = *(const short8*)(basep + (size_t)jj * OUTF + c8 * 8);
#pragma unroll
        for (int m2 = 0; m2 < 8; ++m2) accv[m2] += ww * bf2f((unsigned short)v[m2]);
      }
#pragma unroll
      for (int m2 = 0; m2 < 8; ++m2) {
        accv[m2] += __shfl_xor(accv[m2], 8, 64);
        accv[m2] += __shfl_xor(accv[m2], 16, 64);
        accv[m2] += __shfl_xor(accv[m2], 32, 64);
      }
      if (lane < 8) {
        float4 o0, o1;
        o0.x = accv[0] * inv; o0.y = accv[1] * inv;
        o0.z = accv[2] * inv; o0.w = accv[3] * inv;
        o1.x = accv[4] * inv; o1.y = accv[5] * inv;
        o1.z = accv[6] * inv; o1.w = accv[7] * inv;
        float* op = out + (size_t)n * (NH * OUTF) + h * OUTF + lane * 8;
        *(float4*)op = o0;
        *(float4*)(op + 4) = o1;
      }
    } else {
      // slow path d>64: storage-free, wave-local, no syncthreads (rare)
      const float2 s1i2 = s1v[n];
      const float s1i = h ? s1i2.y : s1i2.x;
      float m = -1e30f;
      for (int p = lane; p < d; p += 64) {
        const int jp = cols[n * CAP + p];
        bool dup = false;
        for (int q = 0; q < p; ++q)
          if (cols[n * CAP + q] == jp) { dup = true; break; }
        if (!dup) {
          const float2 s2j2 = s2v[jp];
          float sc = s1i + (h ? s2j2.y : s2j2.x);
          sc = (sc >= 0.f) ? sc : SLOPE * sc;
          m = fmaxf(m, sc);
        }
      }
#pragma unroll
      for (int s = 32; s > 0; s >>= 1) m = fmaxf(m, __shfl_xor(m, s, 64));
      float ds = 0.f;
      for (int p = lane; p < d; p += 64) {
        const int jp = cols[n * CAP + p];
        bool dup = false;
        for (int q = 0; q < p; ++q)
          if (cols[n * CAP + q] == jp) { dup = true; break; }
        if (!dup) {
          const float2 s2j2 = s2v[jp];
          float sc = s1i + (h ? s2j2.y : s2j2.x);
          sc = (sc >= 0.f) ? sc : SLOPE * sc;
          ds += __expf(sc - m);
        }
      }
#pragma unroll
      for (int s = 32; s > 0; s >>= 1) ds += __shfl_xor(ds, s, 64);
      const float inv = 1.f / ds;
      float acc = 0.f;
      for (int p = 0; p < d; ++p) {
        const int jp = __shfl((lane == (p & 63)) ? cols[n * CAP + p] : 0, p & 63, 64);
        bool dup = false;
        for (int q = 0; q < p; ++q)
          if (cols[n * CAP + q] == jp) { dup = true; break; }
        if (!dup) {
          const float2 s2j2 = s2v[jp];
          float sc = s1i + (h ? s2j2.y : s2j2.x);
          sc = (sc >= 0.f) ? sc : SLOPE * sc;
          const float ww = __expf(sc - m);
          acc += ww * bf2f(basep[(size_t)jp * OUTF + lane]);
        }
      }
      out[(size_t)n * (NH * OUTF) + h * OUTF + lane] = acc * inv;
    }
    __syncthreads();   // protect bm/vmask for next iteration
  }
}

extern "C" void kernel_launch(void* const* d_in, const int* in_sizes, int n_in,
                              void* d_out, int out_size, void* d_ws, size_t ws_size,
                              hipStream_t stream) {
  const float* x  = (const float*)d_in[0];
  const int*   ei = (const int*)d_in[1];
  const float* W  = (const float*)d_in[2];
  const float* a1 = (const float*)d_in[3];
  const float* a2 = (const float*)d_in[4];
  float* out = (float*)d_out;

  char* ws = (char*)d_ws;
  unsigned*       bar = (unsigned*)(ws);                       // 4 KB (page)
  int*            deg = (int*)(ws + 4096);                     // 512 KB (stride 16)
  unsigned short* xhb = (unsigned short*)(ws + (1u << 20));    // 2 MB bf16
  float2*         s1v = (float2*)(ws + (3u << 20));            // 64 KB
  float2*         s2v = (float2*)(ws + (3u << 20) + (64u << 10)); // 64 KB
  int*            cols = (int*)(ws + (4u << 20));              // 8 MB

  hipMemsetAsync(ws, 0, 4096 + (size_t)NN * DEGS * 4, stream); // bar + deg
  fused_kernel<<<NBLK, 256, 0, stream>>>(x, ei, W, a1, a2, bar, deg, cols,
                                         xhb, s1v, s2v, out);
}

// Round 8
// 45.933 us; speedup vs baseline: 3.0072x; 3.0072x over previous
//
#include <hip/hip_runtime.h>

#define NN    8192
#define INF_  256
#define OUTF  64
#define NH    2
#define NE    262144
#define CAP   256
#define DEGS  16
#define SLOPE 0.2f

typedef __attribute__((ext_vector_type(8))) short short8;
typedef __attribute__((ext_vector_type(4))) float f32x4;
typedef __attribute__((ext_vector_type(2))) long long ll2;

__device__ __forceinline__ unsigned short f2bf(float f) {
  unsigned int u = __float_as_uint(f);
  u += 0x7fffu + ((u >> 16) & 1u);   // round-to-nearest-even
  return (unsigned short)(u >> 16);
}

// blocks 0..511: GEMM xh = x@W stripe (16 rows), MFMA, s1/s2 epilogue.
// blocks 512..1023: edge scatter (512 edges/block) with block-local i64 detect.
// No persistent register arrays anywhere (scratch-demotion-proof).
__global__ __launch_bounds__(256) void gemm_edge_kernel(
    const float* __restrict__ x, const int* __restrict__ ei,
    const float* __restrict__ W, const float* __restrict__ a1,
    const float* __restrict__ a2, int* __restrict__ deg,
    int* __restrict__ cols, float* __restrict__ xh,
    float2* __restrict__ s1v, float2* __restrict__ s2v) {
  const int b = blockIdx.x, t = threadIdx.x;

  if (b >= 512) {
    // ---- edge scatter ----
    const int eb = b - 512;
    const int e0 = eb * 512 + t * 2;
    __shared__ int s_nz;
    if (t == 0) s_nz = 0;
    __syncthreads();
    // block-local detect: odd 32-bit words of this block's own i-slice
    if (((const unsigned int*)ei)[2 * e0 + 1] != 0u ||
        ((const unsigned int*)ei)[2 * e0 + 3] != 0u)
      s_nz = 1;
    __syncthreads();
    int i0, j0, i1, j1;
    if (s_nz == 0) {  // int64
      const ll2 a = *(const ll2*)((const long long*)ei + e0);
      const ll2 c = *(const ll2*)((const long long*)ei + NE + e0);
      i0 = (int)a[0]; i1 = (int)a[1]; j0 = (int)c[0]; j1 = (int)c[1];
    } else {
      const int2 a = *(const int2*)(ei + e0);
      const int2 c = *(const int2*)(ei + NE + e0);
      i0 = a.x; i1 = a.y; j0 = c.x; j1 = c.y;
    }
    const int p0 = atomicAdd(&deg[i0 * DEGS], 1);
    if (p0 < CAP) cols[i0 * CAP + p0] = j0;
    const int p1 = atomicAdd(&deg[i1 * DEGS], 1);
    if (p1 < CAP) cols[i1 * CAP + p1] = j1;
    return;
  }

  // ---- GEMM stripe: rows 16b..16b+15; wave w owns col-tiles {2w, 2w+1} ----
  const int l = t & 63, w = t >> 6;
  const int lo = l & 15, hi = l >> 4;
  const int n0 = b * 16;
  __shared__ float p1s[4][16], p2s[4][16];

  const int tc0 = w * 2, tc1 = w * 2 + 1;
  const int h0 = tc0 >> 2, h1 = tc1 >> 2;
  const int col0 = (tc0 * 16 + lo) & 63, col1 = (tc1 * 16 + lo) & 63;
  const float* wp0 = W + (size_t)h0 * (INF_ * OUTF) + (size_t)(hi * 8) * OUTF + col0;
  const float* wp1 = W + (size_t)h1 * (INF_ * OUTF) + (size_t)(hi * 8) * OUTF + col1;
  const float* xp = x + (size_t)(n0 + lo) * INF_ + hi * 8;

  f32x4 acc0 = {0.f, 0.f, 0.f, 0.f};
  f32x4 acc1 = {0.f, 0.f, 0.f, 0.f};

#define KSTEP(ks)                                                              \
  {                                                                            \
    const float4 f0 = *(const float4*)(xp + (ks) * 32);                        \
    const float4 f1 = *(const float4*)(xp + (ks) * 32 + 4);                    \
    short8 a_;                                                                 \
    a_[0] = (short)f2bf(f0.x); a_[1] = (short)f2bf(f0.y);                      \
    a_[2] = (short)f2bf(f0.z); a_[3] = (short)f2bf(f0.w);                      \
    a_[4] = (short)f2bf(f1.x); a_[5] = (short)f2bf(f1.y);                      \
    a_[6] = (short)f2bf(f1.z); a_[7] = (short)f2bf(f1.w);                      \
    const float* wq0 = wp0 + (size_t)(ks) * 32 * OUTF;                         \
    short8 b0_;                                                                \
    b0_[0] = (short)f2bf(wq0[0 * OUTF]); b0_[1] = (short)f2bf(wq0[1 * OUTF]);  \
    b0_[2] = (short)f2bf(wq0[2 * OUTF]); b0_[3] = (short)f2bf(wq0[3 * OUTF]);  \
    b0_[4] = (short)f2bf(wq0[4 * OUTF]); b0_[5] = (short)f2bf(wq0[5 * OUTF]);  \
    b0_[6] = (short)f2bf(wq0[6 * OUTF]); b0_[7] = (short)f2bf(wq0[7 * OUTF]);  \
    acc0 = __builtin_amdgcn_mfma_f32_16x16x32_bf16(a_, b0_, acc0, 0, 0, 0);    \
    const float* wq1 = wp1 + (size_t)(ks) * 32 * OUTF;                         \
    short8 b1_;                                                                \
    b1_[0] = (short)f2bf(wq1[0 * OUTF]); b1_[1] = (short)f2bf(wq1[1 * OUTF]);  \
    b1_[2] = (short)f2bf(wq1[2 * OUTF]); b1_[3] = (short)f2bf(wq1[3 * OUTF]);  \
    b1_[4] = (short)f2bf(wq1[4 * OUTF]); b1_[5] = (short)f2bf(wq1[5 * OUTF]);  \
    b1_[6] = (short)f2bf(wq1[6 * OUTF]); b1_[7] = (short)f2bf(wq1[7 * OUTF]);  \
    acc1 = __builtin_amdgcn_mfma_f32_16x16x32_bf16(a_, b1_, acc1, 0, 0, 0);    \
  }

  KSTEP(0) KSTEP(1) KSTEP(2) KSTEP(3) KSTEP(4) KSTEP(5) KSTEP(6) KSTEP(7)
#undef KSTEP

  // store xh f32 (C/D layout: row = hi*4 + r, col per tile)
  {
    float* o0 = xh + ((size_t)h0 * NN + n0 + hi * 4) * OUTF + col0;
    float* o1 = xh + ((size_t)h1 * NN + n0 + hi * 4) * OUTF + col1;
    o0[0 * OUTF] = acc0[0]; o0[1 * OUTF] = acc0[1];
    o0[2 * OUTF] = acc0[2]; o0[3 * OUTF] = acc0[3];
    o1[0 * OUTF] = acc1[0]; o1[1 * OUTF] = acc1[1];
    o1[2 * OUTF] = acc1[2]; o1[3 * OUTF] = acc1[3];
  }
  // s1/s2 epilogue from f32 accumulator
  const float a10 = a1[h0 * OUTF + col0], a11 = a1[h1 * OUTF + col1];
  const float a20 = a2[h0 * OUTF + col0], a21 = a2[h1 * OUTF + col1];
#pragma unroll
  for (int r = 0; r < 4; ++r) {
    float p1 = acc0[r] * a10 + acc1[r] * a11;
    float p2 = acc0[r] * a20 + acc1[r] * a21;
#pragma unroll
    for (int s = 1; s < 16; s <<= 1) {
      p1 += __shfl_xor(p1, s, 64);
      p2 += __shfl_xor(p2, s, 64);
    }
    if (lo == 0) {
      p1s[w][hi * 4 + r] = p1;
      p2s[w][hi * 4 + r] = p2;
    }
  }
  __syncthreads();
  if (t < 16) {
    float2 v1, v2;
    v1.x = p1s[0][t] + p1s[1][t];  v1.y = p1s[2][t] + p1s[3][t];
    v2.x = p2s[0][t] + p2s[1][t];  v2.y = p2s[2][t] + p2s[3][t];
    s1v[n0 + t] = v1;
    s2v[n0 + t] = v2;
  }
}

// R6-measured agg (~10-13 us): one block (128 thr = 2 waves, wave = head) per
// src node. Fast path d<=64: LDS-bitmap dedup by wave 0, register softmax,
// gather 4 rows per dwordx4 (row-slot r = lane>>4, feat-quad c4 = lane&15).
__global__ __launch_bounds__(128) void agg_kernel(const float* __restrict__ xh,
                                                  const float2* __restrict__ s1v,
                                                  const float2* __restrict__ s2v,
                                                  const int* __restrict__ deg,
                                                  const int* __restrict__ cols,
                                                  float* __restrict__ out) {
  const int i = blockIdx.x;
  const int t = threadIdx.x;
  const int h = t >> 6, lane = t & 63;
  __shared__ unsigned int bm[NN / 32];
  __shared__ unsigned long long vmask;
  __shared__ int   cjs[CAP];
  __shared__ float wts[NH][CAP];
  int d = deg[i * DEGS];
  if (d > CAP) d = CAP;
  bm[t] = 0u; bm[t + 128] = 0u;
  __syncthreads();

  const float* base = xh + (size_t)h * NN * OUTF;
  const int c4 = lane & 15, r = lane >> 4;

  if (d == 0) {  // reference: all-NEG row -> uniform softmax over ALL nodes
    f32x4 acc = {0.f, 0.f, 0.f, 0.f};
    for (int p = r; p < NN; p += 4)
      acc += *(const f32x4*)(base + (size_t)p * OUTF + 4 * c4);
#pragma unroll
    for (int c = 0; c < 4; ++c) {
      acc[c] += __shfl_xor(acc[c], 16, 64);
      acc[c] += __shfl_xor(acc[c], 32, 64);
    }
    if (lane < 16) {
      const float sc = 1.f / (float)NN;
      float4 o;
      o.x = acc[0] * sc; o.y = acc[1] * sc; o.z = acc[2] * sc; o.w = acc[3] * sc;
      *(float4*)(out + (size_t)i * (NH * OUTF) + h * OUTF + 4 * lane) = o;
    }
    return;
  }

  if (d <= 64) {
    int j = 0;
    const bool valid = lane < d;
    if (valid) j = cols[i * CAP + lane];
    if (h == 0) {
      bool dup = false;
      if (valid) {
        const unsigned int old = atomicOr(&bm[j >> 5], 1u << (j & 31));
        dup = (old >> (j & 31)) & 1u;
      }
      const unsigned long long bal = __ballot(valid && !dup);
      if (lane == 0) vmask = bal;
    }
    __syncthreads();
    const bool kp = (vmask >> lane) & 1ull;
    float sc = -1e30f;
    if (kp) {
      const float2 s1i2 = s1v[i];
      const float2 s2j2 = s2v[j];
      sc = (h ? s1i2.y : s1i2.x) + (h ? s2j2.y : s2j2.x);
      sc = (sc >= 0.f) ? sc : SLOPE * sc;
    }
    float m = sc;
#pragma unroll
    for (int s = 32; s > 0; s >>= 1) m = fmaxf(m, __shfl_xor(m, s, 64));
    const float wt = kp ? __expf(sc - m) : 0.f;
    float ds = wt;
#pragma unroll
    for (int s = 32; s > 0; s >>= 1) ds += __shfl_xor(ds, s, 64);
    const float inv = 1.f / ds;

    f32x4 acc = {0.f, 0.f, 0.f, 0.f};
#pragma unroll 2
    for (int p = 0; p < d; p += 4) {
      const int pr = p + r;
      float ww = __shfl(wt, pr, 64);
      int   jj = __shfl(j,  pr, 64);
      ww = (pr < d) ? ww : 0.f;
      jj = (ww > 0.f) ? jj : 0;
      acc += ww * *(const f32x4*)(base + (size_t)jj * OUTF + 4 * c4);
    }
#pragma unroll
    for (int c = 0; c < 4; ++c) {
      acc[c] += __shfl_xor(acc[c], 16, 64);
      acc[c] += __shfl_xor(acc[c], 32, 64);
    }
    if (lane < 16) {
      float4 o;
      o.x = acc[0] * inv; o.y = acc[1] * inv; o.z = acc[2] * inv; o.w = acc[3] * inv;
      *(float4*)(out + (size_t)i * (NH * OUTF) + h * OUTF + 4 * lane) = o;
    }
    return;
  }

  // slow path: 64 < d <= CAP
  for (int p = t; p < d; p += 128) cjs[p] = cols[i * CAP + p];
  __syncthreads();
  if (h == 0) {
    for (int p = lane; p < d; p += 64) {
      const int j = cjs[p];
      const unsigned int old = atomicOr(&bm[j >> 5], 1u << (j & 31));
      if ((old >> (j & 31)) & 1u) cjs[p] = -1;
    }
  }
  __syncthreads();
  const float2 s1i2 = s1v[i];
  const float s1i = h ? s1i2.y : s1i2.x;
  float m = -1e30f;
  for (int p = lane; p < d; p += 64) {
    const int j = cjs[p];
    float sc = -1e30f;
    if (j >= 0) {
      const float2 s2j2 = s2v[j];
      sc = s1i + (h ? s2j2.y : s2j2.x);
      sc = (sc >= 0.f) ? sc : SLOPE * sc;
    }
    wts[h][p] = sc;
    m = fmaxf(m, sc);
  }
#pragma unroll
  for (int s = 32; s > 0; s >>= 1) m = fmaxf(m, __shfl_xor(m, s, 64));
  float ds = 0.f;
  for (int p = lane; p < d; p += 64) {
    const float sc = wts[h][p];
    const float w2 = (sc > -1e29f) ? __expf(sc - m) : 0.f;
    wts[h][p] = w2;
    ds += w2;
  }
#pragma unroll
  for (int s = 32; s > 0; s >>= 1) ds += __shfl_xor(ds, s, 64);
  const float inv = 1.f / ds;
  float acc = 0.f;
  for (int p = 0; p < d; ++p) {
    const float w2 = wts[h][p];
    if (w2 > 0.f) acc += w2 * base[(size_t)cjs[p] * OUTF + lane];
  }
  out[(size_t)i * (NH * OUTF) + h * OUTF + lane] = acc * inv;
}

extern "C" void kernel_launch(void* const* d_in, const int* in_sizes, int n_in,
                              void* d_out, int out_size, void* d_ws, size_t ws_size,
                              hipStream_t stream) {
  const float* x  = (const float*)d_in[0];
  const int*   ei = (const int*)d_in[1];
  const float* W  = (const float*)d_in[2];
  const float* a1 = (const float*)d_in[3];
  const float* a2 = (const float*)d_in[4];
  float* out = (float*)d_out;

  char* ws = (char*)d_ws;
  float*  xh   = (float*)(ws);                               // 4 MB
  float2* s1v  = (float2*)(ws + (4u << 20));                 // 64 KB
  float2* s2v  = (float2*)(ws + (4u << 20) + (64u << 10));   // 64 KB
  int*    deg  = (int*)  (ws + (4u << 20) + (128u << 10));   // 512 KB (stride 16)
  int*    cols = (int*)  (ws + (5u << 20));                  // 8 MB

  hipMemsetAsync(deg, 0, (size_t)NN * DEGS * 4, stream);
  gemm_edge_kernel<<<1024, 256, 0, stream>>>(x, ei, W, a1, a2, deg, cols,
                                             xh, s1v, s2v);
  agg_kernel<<<NN, 128, 0, stream>>>(xh, s1v, s2v, deg, cols, out);
}